// Round 18
// baseline (164.040 us; speedup 1.0000x reference)
//
#include <hip/hip_runtime.h>

#define N_NODES 50000
#define N_EDGES 800000
#define IN_FEATS 256
#define HIDDEN 64
#define OUTF 32
#define SCAN_BLOCKS 196     // ceil(50000/256)

#define NSLICE 64           // edge slices
#define SLICE_E 12500       // N_EDGES / NSLICE
#define NRANGE 4            // node ranges for fill_csr
#define RANGE_N 12800       // nodes per fill range
#define PSTRIDE 51200       // per-slice stride in partial arrays

#define HRANGE 2            // hist ranges (packed 2 nodes/int)
#define HRANGE_N 25600      // nodes per hist range

#define G32_BLOCKS 3125     // N_NODES / 16
#define XH 1600000          // u16 elements per xw1/g1 half: N_NODES*32

typedef __attribute__((ext_vector_type(8))) short bf16x8;
typedef __attribute__((ext_vector_type(4))) float f32x4;
typedef unsigned short u16;

__device__ __forceinline__ unsigned f2bf_pk(float a, float b) {
    union { float f; unsigned u; } x, y;
    x.f = a; y.f = b;
    unsigned lo = x.u + 0x7FFFu + ((x.u >> 16) & 1u);
    unsigned hi = y.u + 0x7FFFu + ((y.u >> 16) & 1u);
    return (lo >> 16) | (hi & 0xFFFF0000u);
}
__device__ __forceinline__ u16 f2bf(float a) {
    union { float f; unsigned u; } x;
    x.f = a;
    return (u16)((x.u + 0x7FFFu + ((x.u >> 16) & 1u)) >> 16);
}
__device__ __forceinline__ float bflo(unsigned v) {
    union { unsigned u; float f; } x; x.u = v << 16; return x.f;
}
__device__ __forceinline__ float bfhi(unsigned v) {
    union { unsigned u; float f; } x; x.u = v & 0xFFFF0000u; return x.f;
}

// ---------------- LDS histogram, 2 nodes packed per int ----------------
__global__ __launch_bounds__(512) void hist_kernel(const int* __restrict__ src,
                                                   const int* __restrict__ dst,
                                                   unsigned char* __restrict__ partial) {
    __shared__ int h[HRANGE_N / 2];     // 12800 ints = 51.2 KB
    const int bid = blockIdx.x;
    const int which = bid & 1;
    const int r = (bid >> 1) & 1;
    const int s = bid >> 2;
    const int tid = threadIdx.x;
    const int lo = r * HRANGE_N;

    for (int i = tid; i < HRANGE_N / 2; i += 512) h[i] = 0;
    __syncthreads();

    const int* arr = which ? dst : src;
    const int e0 = s * SLICE_E;
    for (int j = tid; j < SLICE_E; j += 512) {
        int v = arr[e0 + j] - lo;
        if ((unsigned)v < HRANGE_N) atomicAdd(&h[v >> 1], 1 << ((v & 1) << 4));
    }
    __syncthreads();

    unsigned char* p = partial + (size_t)which * NSLICE * PSTRIDE + (size_t)s * PSTRIDE + lo;
    for (int i = tid; i < HRANGE_N / 2; i += 512) {
        int c = h[i];
        p[i * 2 + 0] = (unsigned char)(c & 0xFFFF);
        p[i * 2 + 1] = (unsigned char)((unsigned)c >> 16);
    }
}

// ---------------- reduce partials -> norms + block-level exclusive scan ----------------
__global__ __launch_bounds__(256) void reduce_scan_kernel(unsigned char* __restrict__ partial,
                                                          int* __restrict__ row_start,
                                                          int* __restrict__ block_sums,
                                                          float* __restrict__ norm_out,
                                                          float* __restrict__ norm_in) {
    __shared__ int sh[256];
    int i = blockIdx.x * 256 + threadIdx.x;
    int run = 0;
    if (i < N_NODES) {
        const unsigned char* ps = partial + i;                      // src partials
        unsigned char* pd = partial + (size_t)NSLICE * PSTRIDE + i; // dst partials
        int so = 0;
#pragma unroll 8
        for (int s = 0; s < NSLICE; ++s) so += ps[(size_t)s * PSTRIDE];
        norm_out[i] = rsqrtf(fmaxf((float)so, 1.0f));
#pragma unroll 8
        for (int s = 0; s < NSLICE; ++s) {
            int c = pd[(size_t)s * PSTRIDE];
            pd[(size_t)s * PSTRIDE] = (unsigned char)run;   // exclusive prefix
            run += c;
        }
        norm_in[i] = rsqrtf(fmaxf((float)run, 1.0f));
    }
    sh[threadIdx.x] = run;
    __syncthreads();
#pragma unroll
    for (int off = 1; off < 256; off <<= 1) {
        int t = (threadIdx.x >= off) ? sh[threadIdx.x - off] : 0;
        __syncthreads();
        sh[threadIdx.x] += t;
        __syncthreads();
    }
    if (i < N_NODES) row_start[i] = sh[threadIdx.x] - run;
    if (threadIdx.x == 255) block_sums[blockIdx.x] = sh[255];
}

// ---------------- scan of block sums folded into the add pass ----------------
__global__ __launch_bounds__(256) void scan3_kernel(int* __restrict__ row_start,
                                                    const int* __restrict__ block_sums) {
    __shared__ int s[256];
    int v = (threadIdx.x < SCAN_BLOCKS) ? block_sums[threadIdx.x] : 0;
    s[threadIdx.x] = v;
    __syncthreads();
#pragma unroll
    for (int off = 1; off < 256; off <<= 1) {
        int t = (threadIdx.x >= off) ? s[threadIdx.x - off] : 0;
        __syncthreads();
        s[threadIdx.x] += t;
        __syncthreads();
    }
    int base = (blockIdx.x == 0) ? 0 : s[blockIdx.x - 1];   // exclusive prefix for this block
    int i = blockIdx.x * 256 + threadIdx.x;
    if (i < N_NODES) row_start[i] += base;
    if (i == 0) row_start[N_NODES] = N_EDGES;
}

// ---------------- CSR fill with LDS cursors (u16 ids): block = (slice, range) ----------------
__global__ __launch_bounds__(512) void fill_csr_kernel(const int* __restrict__ src,
                                                       const int* __restrict__ dst,
                                                       const int* __restrict__ row_start,
                                                       const unsigned char* __restrict__ rel,
                                                       u16* __restrict__ csr16) {
    __shared__ int cur[RANGE_N];        // 51200 B
    const int bid = blockIdx.x;
    const int r = bid & 3;
    const int s = bid >> 2;
    const int tid = threadIdx.x;
    const int lo = r * RANGE_N;

    const unsigned char* relp = rel + (size_t)s * PSTRIDE;
    for (int i = tid; i < RANGE_N; i += 512) {
        int node = lo + i;
        cur[i] = (node < N_NODES) ? row_start[node] + (int)relp[node] : 0;
    }
    __syncthreads();

    const int e0 = s * SLICE_E;
    for (int j = tid; j < SLICE_E; j += 512) {
        int d = dst[e0 + j] - lo;
        if ((unsigned)d < RANGE_N) {
            int pos = atomicAdd(&cur[d], 1);
            csr16[pos] = (u16)src[e0 + j];
        }
    }
}

// ---------------- GEMM1: bf16 MFMA 16x16x32, 64x64 tile, 2 chunks of BK=128 ----------------
// Output layout: xw1[2][N][32] (feature-half major) for L2-phased gathering.
#define AST 136    // shorts per LDS row
__global__ __launch_bounds__(256) void gemm1_kernel(const float* __restrict__ x,
                                                    const float* __restrict__ W1,
                                                    const float* __restrict__ norm_out,
                                                    u16* __restrict__ xw1) {
    __shared__ short As[64 * AST];   // x tile, bf16, [row][k]
    __shared__ short Bt[64 * AST];   // W1 chunk, bf16, [col][k]
    const int tid = threadIdx.x;
    const int n0 = blockIdx.x * 64;

    const f32x4 zero4 = {0.f, 0.f, 0.f, 0.f};
    f32x4 acc[4] = {zero4, zero4, zero4, zero4};

    const int srow = tid >> 2;          // staging row 0..63
    const int sseg = tid & 3;           // 32-k segment
    const int grow = n0 + srow;
    const bool grow_ok = grow < N_NODES;

    const int w = tid >> 6;             // wave 0..3 -> rows w*16..
    const int l = tid & 63;

    for (int c = 0; c < 2; ++c) {
        if (c) __syncthreads();
        {
            const float* xp = x + (size_t)grow * IN_FEATS + c * 128 + sseg * 32;
            short* ap = As + srow * AST + sseg * 32;
#pragma unroll
            for (int j = 0; j < 8; ++j) {
                float4 v = make_float4(0.f, 0.f, 0.f, 0.f);
                if (grow_ok) v = *(const float4*)(xp + j * 4);
                unsigned p0 = f2bf_pk(v.x, v.y);
                unsigned p1 = f2bf_pk(v.z, v.w);
                *(uint2*)(ap + j * 4) = make_uint2(p0, p1);
            }
        }
        {
#pragma unroll
            for (int it = 0; it < 16; ++it) {
                int flat = tid + it * 256;
                int kp = flat >> 6;             // k-pair 0..63
                int col = flat & 63;
                int k = c * 128 + kp * 2;
                float w0 = W1[(size_t)k * HIDDEN + col];
                float w1 = W1[(size_t)(k + 1) * HIDDEN + col];
                *(unsigned*)(Bt + col * AST + kp * 2) = f2bf_pk(w0, w1);
            }
        }
        __syncthreads();

        const short* ap = As + (w * 16 + (l & 15)) * AST + (l >> 4) * 8;
        const short* bp = Bt + (l & 15) * AST + (l >> 4) * 8;
#pragma unroll
        for (int ks = 0; ks < 4; ++ks) {
            bf16x8 af = *(const bf16x8*)(ap + ks * 32);
#pragma unroll
            for (int ct = 0; ct < 4; ++ct) {
                bf16x8 bfv = *(const bf16x8*)(bp + ct * 16 * AST + ks * 32);
                acc[ct] = __builtin_amdgcn_mfma_f32_16x16x32_bf16(af, bfv, acc[ct], 0, 0, 0);
            }
        }
    }

    // D[row][col]: row=(l>>4)*4+j, col = cbase + ct*16; half = ct>>1
    const int rbase = n0 + w * 16 + (l >> 4) * 4;
    const int cbase = l & 15;
#pragma unroll
    for (int j = 0; j < 4; ++j) {
        int row = rbase + j;
        if (row < N_NODES) {
            float nrm = norm_out[row];
#pragma unroll
            for (int ct = 0; ct < 4; ++ct) {
                int half = ct >> 1;
                int fl = cbase + (ct & 1) * 16;
                xw1[(size_t)half * XH + (size_t)row * 32 + fl] = f2bf(acc[ct][j] * nrm);
            }
        }
    }
}

// ---------------- gather64 half-pass: 16 nodes/block, 4 slots x 16 pairs ----------------
// Reads xw1 half h (3.2 MB, fits per-XCD L2); writes relu(g1) half h.
__global__ __launch_bounds__(256) void gather64h_kernel(const int* __restrict__ row_start,
                                                        const u16* __restrict__ csr16,
                                                        const u16* __restrict__ xw1,
                                                        const float* __restrict__ norm_in,
                                                        const float* __restrict__ b1,
                                                        u16* __restrict__ g1,
                                                        int h) {
    const int tid = threadIdx.x;
    const int w = tid >> 6;
    const int l = tid & 63;
    const int p = l & 15;       // feature pair -> local feats 2p, 2p+1
    const int gsl = l >> 4;     // edge slot 0..3
    const int n0 = blockIdx.x * 16;
    const u16* xh = xw1 + (size_t)h * XH;
    u16* gh = g1 + (size_t)h * XH;
    const float bx = b1[h * 32 + 2 * p];
    const float by = b1[h * 32 + 2 * p + 1];

#pragma unroll
    for (int i4 = 0; i4 < 4; ++i4) {
        int n = n0 + w * 4 + i4;
        int beg = row_start[n], end = row_start[n + 1];
        float ax = 0.f, ay = 0.f;
        int i = beg;
        for (; i + 16 <= end; i += 16) {        // 4 loads in flight
            int s0 = __builtin_nontemporal_load(csr16 + i + gsl);
            int s1 = __builtin_nontemporal_load(csr16 + i + 4 + gsl);
            int s2 = __builtin_nontemporal_load(csr16 + i + 8 + gsl);
            int s3 = __builtin_nontemporal_load(csr16 + i + 12 + gsl);
            unsigned v0 = *(const unsigned*)(xh + (size_t)s0 * 32 + 2 * p);
            unsigned v1 = *(const unsigned*)(xh + (size_t)s1 * 32 + 2 * p);
            unsigned v2 = *(const unsigned*)(xh + (size_t)s2 * 32 + 2 * p);
            unsigned v3 = *(const unsigned*)(xh + (size_t)s3 * 32 + 2 * p);
            ax += (bflo(v0) + bflo(v1)) + (bflo(v2) + bflo(v3));
            ay += (bfhi(v0) + bfhi(v1)) + (bfhi(v2) + bfhi(v3));
        }
        for (; i + 8 <= end; i += 8) {
            int s0 = __builtin_nontemporal_load(csr16 + i + gsl);
            int s1 = __builtin_nontemporal_load(csr16 + i + 4 + gsl);
            unsigned v0 = *(const unsigned*)(xh + (size_t)s0 * 32 + 2 * p);
            unsigned v1 = *(const unsigned*)(xh + (size_t)s1 * 32 + 2 * p);
            ax += bflo(v0) + bflo(v1);
            ay += bfhi(v0) + bfhi(v1);
        }
        for (; i + 4 <= end; i += 4) {
            int s0 = __builtin_nontemporal_load(csr16 + i + gsl);
            unsigned v0 = *(const unsigned*)(xh + (size_t)s0 * 32 + 2 * p);
            ax += bflo(v0);
            ay += bfhi(v0);
        }
        int t = end - i;
        if (gsl < t) {
            int s0 = __builtin_nontemporal_load(csr16 + i + gsl);
            unsigned v0 = *(const unsigned*)(xh + (size_t)s0 * 32 + 2 * p);
            ax += bflo(v0);
            ay += bfhi(v0);
        }
        ax += __shfl_xor(ax, 16); ax += __shfl_xor(ax, 32);
        ay += __shfl_xor(ay, 16); ay += __shfl_xor(ay, 32);
        if (gsl == 0) {
            float nin = norm_in[n];
            float rx = fmaxf(ax * nin + bx, 0.f);
            float ry = fmaxf(ay * nin + by, 0.f);
            __builtin_nontemporal_store(f2bf_pk(rx, ry),
                                        (unsigned*)(gh + (size_t)n * 32 + 2 * p));
        }
    }
}

// ---------------- GEMM2: xw2[n] = (g1[n] @ W2) * norm_out[n], bf16 in/out ----------------
__global__ __launch_bounds__(256) void gemm2_kernel(const u16* __restrict__ g1,
                                                    const float* __restrict__ W2,
                                                    const float* __restrict__ norm_out,
                                                    u16* __restrict__ xw2) {
    __shared__ float gs[8][64];
    __shared__ float ws[HIDDEN * OUTF];
    const int tid = threadIdx.x;
    const int n0 = blockIdx.x * 8;

#pragma unroll
    for (int i = 0; i < 8; ++i) ws[tid + i * 256] = W2[tid + i * 256];
    {
        int r = tid >> 5, oo = tid & 31;
        int h = oo >> 4, pp = oo & 15;
        unsigned v = *(const unsigned*)(g1 + (size_t)h * XH + (size_t)(n0 + r) * 32 + 2 * pp);
        gs[r][h * 32 + 2 * pp]     = bflo(v);
        gs[r][h * 32 + 2 * pp + 1] = bfhi(v);
    }
    __syncthreads();

    const int o = tid & 31;
    const int r = tid >> 5;
    float acc = 0.f;
#pragma unroll 8
    for (int k = 0; k < 64; ++k) acc += gs[r][k] * ws[k * 32 + o];
    int row = n0 + r;
    xw2[(size_t)row * 32 + o] = f2bf(acc * norm_out[row]);
}

// ---------------- gather32 + weighted partial: 16 nodes/block, 16-edge-deep MLP ----------------
__global__ __launch_bounds__(256) void gather32_kernel(const int* __restrict__ row_start,
                                                       const u16* __restrict__ csr16,
                                                       const u16* __restrict__ xw2,
                                                       const float* __restrict__ norm_in,
                                                       const float* __restrict__ b2,
                                                       const float* __restrict__ fc_w,
                                                       float* __restrict__ red) {
    __shared__ float sout[OUTF];
    const int tid = threadIdx.x;
    if (tid < OUTF) sout[tid] = 0.f;
    __syncthreads();

    const int w = tid >> 6;
    const int l = tid & 63;
    const int p = l & 15;       // feature pair -> feats 2p, 2p+1
    const int gsl = l >> 4;     // edge slot 0..3
    const int n0 = blockIdx.x * 16;
    float tx = 0.f, ty = 0.f;

#pragma unroll
    for (int i4 = 0; i4 < 4; ++i4) {
        int n = n0 + w * 4 + i4;
        int beg = row_start[n], end = row_start[n + 1];
        float ax = 0.f, ay = 0.f;
        int i = beg;
        for (; i + 16 <= end; i += 16) {        // 4 loads in flight
            int s0 = csr16[i + gsl];
            int s1 = csr16[i + 4 + gsl];
            int s2 = csr16[i + 8 + gsl];
            int s3 = csr16[i + 12 + gsl];
            unsigned v0 = *(const unsigned*)(xw2 + (size_t)s0 * 32 + 2 * p);
            unsigned v1 = *(const unsigned*)(xw2 + (size_t)s1 * 32 + 2 * p);
            unsigned v2 = *(const unsigned*)(xw2 + (size_t)s2 * 32 + 2 * p);
            unsigned v3 = *(const unsigned*)(xw2 + (size_t)s3 * 32 + 2 * p);
            ax += (bflo(v0) + bflo(v1)) + (bflo(v2) + bflo(v3));
            ay += (bfhi(v0) + bfhi(v1)) + (bfhi(v2) + bfhi(v3));
        }
        for (; i + 8 <= end; i += 8) {
            int s0 = csr16[i + gsl];
            int s1 = csr16[i + 4 + gsl];
            unsigned v0 = *(const unsigned*)(xw2 + (size_t)s0 * 32 + 2 * p);
            unsigned v1 = *(const unsigned*)(xw2 + (size_t)s1 * 32 + 2 * p);
            ax += bflo(v0) + bflo(v1);
            ay += bfhi(v0) + bfhi(v1);
        }
        for (; i + 4 <= end; i += 4) {
            int s0 = csr16[i + gsl];
            unsigned v0 = *(const unsigned*)(xw2 + (size_t)s0 * 32 + 2 * p);
            ax += bflo(v0);
            ay += bfhi(v0);
        }
        int t = end - i;
        if (gsl < t) {
            int s0 = csr16[i + gsl];
            unsigned v0 = *(const unsigned*)(xw2 + (size_t)s0 * 32 + 2 * p);
            ax += bflo(v0);
            ay += bfhi(v0);
        }
        ax += __shfl_xor(ax, 16); ax += __shfl_xor(ax, 32);
        ay += __shfl_xor(ay, 16); ay += __shfl_xor(ay, 32);
        if (gsl == 0) {
            float nin = norm_in[n], fw = fc_w[n];
            tx += fmaxf(ax * nin + b2[2 * p], 0.f) * fw;
            ty += fmaxf(ay * nin + b2[2 * p + 1], 0.f) * fw;
        }
    }
    if (gsl == 0) {
        atomicAdd(&sout[2 * p], tx);        // LDS atomics, 4 waves -> 4-way
        atomicAdd(&sout[2 * p + 1], ty);
    }
    __syncthreads();
    if (tid < OUTF) red[(size_t)blockIdx.x * OUTF + tid] = sout[tid];
}

// ---------------- final: 32 blocks, block o sums column o of red ----------------
__global__ __launch_bounds__(256) void reduce2_kernel(const float* __restrict__ red,
                                                      const float* __restrict__ fc_b,
                                                      float* __restrict__ out) {
    __shared__ float s[256];
    const int tid = threadIdx.x;
    const int o = blockIdx.x;       // feature 0..31
    float a = 0.f;
    for (int r = tid; r < G32_BLOCKS; r += 256)
        a += red[(size_t)r * OUTF + o];
    s[tid] = a;
    __syncthreads();
#pragma unroll
    for (int off = 128; off > 0; off >>= 1) {
        if (tid < off) s[tid] += s[tid + off];
        __syncthreads();
    }
    if (tid == 0) out[o] = s[0] + fc_b[0];
}

extern "C" void kernel_launch(void* const* d_in, const int* in_sizes, int n_in,
                              void* d_out, int out_size, void* d_ws, size_t ws_size,
                              hipStream_t stream) {
    const float* x    = (const float*)d_in[0];
    const int*   src  = (const int*)d_in[1];
    const int*   dst  = (const int*)d_in[2];
    const float* W1   = (const float*)d_in[3];
    const float* b1   = (const float*)d_in[4];
    const float* W2   = (const float*)d_in[5];
    const float* b2   = (const float*)d_in[6];
    const float* fc_w = (const float*)d_in[7];
    const float* fc_b = (const float*)d_in[8];
    float* out = (float*)d_out;

    // ---- workspace layout (all 4B-aligned) ----
    u16* csr16      = (u16*)d_ws;                       // 800000 u16 (1.6 MB)
    int* row_start  = (int*)(csr16 + 800000);           // 50001 (+pad)
    int* block_sums = row_start + 50004;                // 256 (+pad)
    u16* xw1_buf    = (u16*)(block_sums + 260);         // [2][N][32] = 3.2M u16
    u16* xw2_buf    = xw1_buf + 2 * XH;                 // 1.6M u16
    u16* g1_buf     = xw2_buf + 1600000;                // [2][N][32] = 3.2M u16
    float* norm_out = (float*)(g1_buf + 2 * XH);        // 50000
    float* norm_in  = norm_out + 50000;                 // 50000
    float* red      = norm_in + 50000;                  // 3125*32 = 100000
    unsigned char* partial = (unsigned char*)(red + 100000); // 2*64*51200 B
    unsigned char* rel = partial + (size_t)NSLICE * PSTRIDE;

    // ---- CSR build (no global atomics anywhere) ----
    hist_kernel<<<NSLICE * HRANGE * 2, 512, 0, stream>>>(src, dst, partial);
    reduce_scan_kernel<<<SCAN_BLOCKS, 256, 0, stream>>>(partial, row_start, block_sums,
                                                        norm_out, norm_in);
    scan3_kernel<<<SCAN_BLOCKS, 256, 0, stream>>>(row_start, block_sums);
    fill_csr_kernel<<<NSLICE * NRANGE, 512, 0, stream>>>(src, dst, row_start, rel, csr16);

    // ---- layer 1 GEMM (bf16 MFMA, half-split output layout) ----
    gemm1_kernel<<<(N_NODES + 63) / 64, 256, 0, stream>>>(x, W1, norm_out, xw1_buf);

    // ---- layer 1 gather, two L2-phased half passes ----
    gather64h_kernel<<<G32_BLOCKS, 256, 0, stream>>>(row_start, csr16, xw1_buf,
                                                     norm_in, b1, g1_buf, 0);
    gather64h_kernel<<<G32_BLOCKS, 256, 0, stream>>>(row_start, csr16, xw1_buf,
                                                     norm_in, b1, g1_buf, 1);

    // ---- layer 2 GEMM ----
    gemm2_kernel<<<N_NODES / 8, 256, 0, stream>>>(g1_buf, W2, norm_out, xw2_buf);

    // ---- gather32 partials + final reduce ----
    gather32_kernel<<<G32_BLOCKS, 256, 0, stream>>>(row_start, csr16, xw2_buf,
                                                    norm_in, b2, fc_w, red);
    reduce2_kernel<<<OUTF, 256, 0, stream>>>(red, fc_b, out);
}

// Round 19
// 146.756 us; speedup vs baseline: 1.1178x; 1.1178x over previous
//
#include <hip/hip_runtime.h>

#define N_NODES 50000
#define N_EDGES 800000
#define IN_FEATS 256
#define HIDDEN 64
#define OUTF 32
#define SCAN_BLOCKS 196     // ceil(50000/256)

#define NSLICE 64           // edge slices
#define SLICE_E 12500       // N_EDGES / NSLICE
#define NRANGE 4            // node ranges for fill_csr
#define RANGE_N 12800       // nodes per fill range
#define PSTRIDE 51200       // per-slice stride in partial arrays

#define HRANGE 2            // hist ranges (packed 2 nodes/int)
#define HRANGE_N 25600      // nodes per hist range

#define G32_BLOCKS 3125     // N_NODES / 16

typedef __attribute__((ext_vector_type(8))) short bf16x8;
typedef __attribute__((ext_vector_type(4))) float f32x4;
typedef unsigned short u16;

__device__ __forceinline__ unsigned f2bf_pk(float a, float b) {
    union { float f; unsigned u; } x, y;
    x.f = a; y.f = b;
    unsigned lo = x.u + 0x7FFFu + ((x.u >> 16) & 1u);
    unsigned hi = y.u + 0x7FFFu + ((y.u >> 16) & 1u);
    return (lo >> 16) | (hi & 0xFFFF0000u);
}
__device__ __forceinline__ u16 f2bf(float a) {
    union { float f; unsigned u; } x;
    x.f = a;
    return (u16)((x.u + 0x7FFFu + ((x.u >> 16) & 1u)) >> 16);
}
__device__ __forceinline__ float bflo(unsigned v) {
    union { unsigned u; float f; } x; x.u = v << 16; return x.f;
}
__device__ __forceinline__ float bfhi(unsigned v) {
    union { unsigned u; float f; } x; x.u = v & 0xFFFF0000u; return x.f;
}

// ---------------- LDS histogram, 2 nodes packed per int ----------------
__global__ __launch_bounds__(512) void hist_kernel(const int* __restrict__ src,
                                                   const int* __restrict__ dst,
                                                   unsigned char* __restrict__ partial) {
    __shared__ int h[HRANGE_N / 2];     // 12800 ints = 51.2 KB
    const int bid = blockIdx.x;
    const int which = bid & 1;
    const int r = (bid >> 1) & 1;
    const int s = bid >> 2;
    const int tid = threadIdx.x;
    const int lo = r * HRANGE_N;

    for (int i = tid; i < HRANGE_N / 2; i += 512) h[i] = 0;
    __syncthreads();

    const int* arr = which ? dst : src;
    const int e0 = s * SLICE_E;
    for (int j = tid; j < SLICE_E; j += 512) {
        int v = arr[e0 + j] - lo;
        if ((unsigned)v < HRANGE_N) atomicAdd(&h[v >> 1], 1 << ((v & 1) << 4));
    }
    __syncthreads();

    unsigned char* p = partial + (size_t)which * NSLICE * PSTRIDE + (size_t)s * PSTRIDE + lo;
    for (int i = tid; i < HRANGE_N / 2; i += 512) {
        int c = h[i];
        p[i * 2 + 0] = (unsigned char)(c & 0xFFFF);
        p[i * 2 + 1] = (unsigned char)((unsigned)c >> 16);
    }
}

// ---------------- reduce partials -> norms + block-level exclusive scan ----------------
__global__ __launch_bounds__(256) void reduce_scan_kernel(unsigned char* __restrict__ partial,
                                                          int* __restrict__ row_start,
                                                          int* __restrict__ block_sums,
                                                          float* __restrict__ norm_out,
                                                          float* __restrict__ norm_in) {
    __shared__ int sh[256];
    int i = blockIdx.x * 256 + threadIdx.x;
    int run = 0;
    if (i < N_NODES) {
        const unsigned char* ps = partial + i;                      // src partials
        unsigned char* pd = partial + (size_t)NSLICE * PSTRIDE + i; // dst partials
        int so = 0;
#pragma unroll 8
        for (int s = 0; s < NSLICE; ++s) so += ps[(size_t)s * PSTRIDE];
        norm_out[i] = rsqrtf(fmaxf((float)so, 1.0f));
#pragma unroll 8
        for (int s = 0; s < NSLICE; ++s) {
            int c = pd[(size_t)s * PSTRIDE];
            pd[(size_t)s * PSTRIDE] = (unsigned char)run;   // exclusive prefix
            run += c;
        }
        norm_in[i] = rsqrtf(fmaxf((float)run, 1.0f));
    }
    sh[threadIdx.x] = run;
    __syncthreads();
#pragma unroll
    for (int off = 1; off < 256; off <<= 1) {
        int t = (threadIdx.x >= off) ? sh[threadIdx.x - off] : 0;
        __syncthreads();
        sh[threadIdx.x] += t;
        __syncthreads();
    }
    if (i < N_NODES) row_start[i] = sh[threadIdx.x] - run;
    if (threadIdx.x == 255) block_sums[blockIdx.x] = sh[255];
}

// ---------------- scan of block sums folded into the add pass ----------------
__global__ __launch_bounds__(256) void scan3_kernel(int* __restrict__ row_start,
                                                    const int* __restrict__ block_sums) {
    __shared__ int s[256];
    int v = (threadIdx.x < SCAN_BLOCKS) ? block_sums[threadIdx.x] : 0;
    s[threadIdx.x] = v;
    __syncthreads();
#pragma unroll
    for (int off = 1; off < 256; off <<= 1) {
        int t = (threadIdx.x >= off) ? s[threadIdx.x - off] : 0;
        __syncthreads();
        s[threadIdx.x] += t;
        __syncthreads();
    }
    int base = (blockIdx.x == 0) ? 0 : s[blockIdx.x - 1];   // exclusive prefix for this block
    int i = blockIdx.x * 256 + threadIdx.x;
    if (i < N_NODES) row_start[i] += base;
    if (i == 0) row_start[N_NODES] = N_EDGES;
}

// ---------------- CSR fill with LDS cursors (u16 ids): block = (slice, range) ----------------
__global__ __launch_bounds__(512) void fill_csr_kernel(const int* __restrict__ src,
                                                       const int* __restrict__ dst,
                                                       const int* __restrict__ row_start,
                                                       const unsigned char* __restrict__ rel,
                                                       u16* __restrict__ csr16) {
    __shared__ int cur[RANGE_N];        // 51200 B
    const int bid = blockIdx.x;
    const int r = bid & 3;
    const int s = bid >> 2;
    const int tid = threadIdx.x;
    const int lo = r * RANGE_N;

    const unsigned char* relp = rel + (size_t)s * PSTRIDE;
    for (int i = tid; i < RANGE_N; i += 512) {
        int node = lo + i;
        cur[i] = (node < N_NODES) ? row_start[node] + (int)relp[node] : 0;
    }
    __syncthreads();

    const int e0 = s * SLICE_E;
    for (int j = tid; j < SLICE_E; j += 512) {
        int d = dst[e0 + j] - lo;
        if ((unsigned)d < RANGE_N) {
            int pos = atomicAdd(&cur[d], 1);
            csr16[pos] = (u16)src[e0 + j];
        }
    }
}

// ---------------- GEMM1: bf16 MFMA 16x16x32, 64x64 tile, 2 chunks of BK=128 ----------------
#define AST 136    // shorts per LDS row
__global__ __launch_bounds__(256) void gemm1_kernel(const float* __restrict__ x,
                                                    const float* __restrict__ W1,
                                                    const float* __restrict__ norm_out,
                                                    u16* __restrict__ xw1) {
    __shared__ short As[64 * AST];   // x tile, bf16, [row][k]
    __shared__ short Bt[64 * AST];   // W1 chunk, bf16, [col][k]
    const int tid = threadIdx.x;
    const int n0 = blockIdx.x * 64;

    const f32x4 zero4 = {0.f, 0.f, 0.f, 0.f};
    f32x4 acc[4] = {zero4, zero4, zero4, zero4};

    const int srow = tid >> 2;          // staging row 0..63
    const int sseg = tid & 3;           // 32-k segment
    const int grow = n0 + srow;
    const bool grow_ok = grow < N_NODES;

    const int w = tid >> 6;             // wave 0..3 -> rows w*16..
    const int l = tid & 63;

    for (int c = 0; c < 2; ++c) {
        if (c) __syncthreads();
        {
            const float* xp = x + (size_t)grow * IN_FEATS + c * 128 + sseg * 32;
            short* ap = As + srow * AST + sseg * 32;
#pragma unroll
            for (int j = 0; j < 8; ++j) {
                float4 v = make_float4(0.f, 0.f, 0.f, 0.f);
                if (grow_ok) v = *(const float4*)(xp + j * 4);
                unsigned p0 = f2bf_pk(v.x, v.y);
                unsigned p1 = f2bf_pk(v.z, v.w);
                *(uint2*)(ap + j * 4) = make_uint2(p0, p1);
            }
        }
        {
#pragma unroll
            for (int it = 0; it < 16; ++it) {
                int flat = tid + it * 256;
                int kp = flat >> 6;             // k-pair 0..63
                int col = flat & 63;
                int k = c * 128 + kp * 2;
                float w0 = W1[(size_t)k * HIDDEN + col];
                float w1 = W1[(size_t)(k + 1) * HIDDEN + col];
                *(unsigned*)(Bt + col * AST + kp * 2) = f2bf_pk(w0, w1);
            }
        }
        __syncthreads();

        const short* ap = As + (w * 16 + (l & 15)) * AST + (l >> 4) * 8;
        const short* bp = Bt + (l & 15) * AST + (l >> 4) * 8;
#pragma unroll
        for (int ks = 0; ks < 4; ++ks) {
            bf16x8 af = *(const bf16x8*)(ap + ks * 32);
#pragma unroll
            for (int ct = 0; ct < 4; ++ct) {
                bf16x8 bfv = *(const bf16x8*)(bp + ct * 16 * AST + ks * 32);
                acc[ct] = __builtin_amdgcn_mfma_f32_16x16x32_bf16(af, bfv, acc[ct], 0, 0, 0);
            }
        }
    }

    const int rbase = n0 + w * 16 + (l >> 4) * 4;
    const int cbase = l & 15;
#pragma unroll
    for (int j = 0; j < 4; ++j) {
        int row = rbase + j;
        if (row < N_NODES) {
            float nrm = norm_out[row];
            u16* orow = xw1 + (size_t)row * HIDDEN + cbase;
#pragma unroll
            for (int ct = 0; ct < 4; ++ct)
                orow[ct * 16] = f2bf(acc[ct][j] * nrm);
        }
    }
}

// ---------------- fused gather64 + gemm2: 16 nodes/block, 16-edge-deep MLP ----------------
__global__ __launch_bounds__(256) void gather64_gemm2_kernel(const int* __restrict__ row_start,
                                                             const u16* __restrict__ csr16,
                                                             const u16* __restrict__ xw1,
                                                             const float* __restrict__ norm_in,
                                                             const float* __restrict__ b1,
                                                             const float* __restrict__ W2,
                                                             const float* __restrict__ norm_out,
                                                             u16* __restrict__ xw2) {
    __shared__ float gs[16][68];         // g1 tile
    __shared__ float ws[HIDDEN * OUTF];  // W2, 8 KB
    const int tid = threadIdx.x;
#pragma unroll
    for (int i = 0; i < 8; ++i) ws[tid + i * 256] = W2[tid + i * 256];

    const int w = tid >> 6;
    const int l = tid & 63;
    const int p = l & 31;       // feature pair -> feats 2p, 2p+1
    const int gsl = l >> 5;     // edge slot 0/1
    const int n0 = blockIdx.x * 16;

#pragma unroll
    for (int i4 = 0; i4 < 4; ++i4) {
        int nl = w * 4 + i4;
        int n = n0 + nl;
        int beg = row_start[n], end = row_start[n + 1];
        float ax = 0.f, ay = 0.f;
        int i = beg;
        for (; i + 16 <= end; i += 16) {        // 8 loads in flight
            int s0 = __builtin_nontemporal_load(csr16 + i + 0 + gsl);
            int s1 = __builtin_nontemporal_load(csr16 + i + 2 + gsl);
            int s2 = __builtin_nontemporal_load(csr16 + i + 4 + gsl);
            int s3 = __builtin_nontemporal_load(csr16 + i + 6 + gsl);
            int s4 = __builtin_nontemporal_load(csr16 + i + 8 + gsl);
            int s5 = __builtin_nontemporal_load(csr16 + i + 10 + gsl);
            int s6 = __builtin_nontemporal_load(csr16 + i + 12 + gsl);
            int s7 = __builtin_nontemporal_load(csr16 + i + 14 + gsl);
            unsigned v0 = *(const unsigned*)(xw1 + (size_t)s0 * 64 + 2 * p);
            unsigned v1 = *(const unsigned*)(xw1 + (size_t)s1 * 64 + 2 * p);
            unsigned v2 = *(const unsigned*)(xw1 + (size_t)s2 * 64 + 2 * p);
            unsigned v3 = *(const unsigned*)(xw1 + (size_t)s3 * 64 + 2 * p);
            unsigned v4 = *(const unsigned*)(xw1 + (size_t)s4 * 64 + 2 * p);
            unsigned v5 = *(const unsigned*)(xw1 + (size_t)s5 * 64 + 2 * p);
            unsigned v6 = *(const unsigned*)(xw1 + (size_t)s6 * 64 + 2 * p);
            unsigned v7 = *(const unsigned*)(xw1 + (size_t)s7 * 64 + 2 * p);
            ax += ((bflo(v0) + bflo(v1)) + (bflo(v2) + bflo(v3))) +
                  ((bflo(v4) + bflo(v5)) + (bflo(v6) + bflo(v7)));
            ay += ((bfhi(v0) + bfhi(v1)) + (bfhi(v2) + bfhi(v3))) +
                  ((bfhi(v4) + bfhi(v5)) + (bfhi(v6) + bfhi(v7)));
        }
        for (; i + 8 <= end; i += 8) {
            int s0 = __builtin_nontemporal_load(csr16 + i + gsl);
            int s1 = __builtin_nontemporal_load(csr16 + i + 2 + gsl);
            int s2 = __builtin_nontemporal_load(csr16 + i + 4 + gsl);
            int s3 = __builtin_nontemporal_load(csr16 + i + 6 + gsl);
            unsigned v0 = *(const unsigned*)(xw1 + (size_t)s0 * 64 + 2 * p);
            unsigned v1 = *(const unsigned*)(xw1 + (size_t)s1 * 64 + 2 * p);
            unsigned v2 = *(const unsigned*)(xw1 + (size_t)s2 * 64 + 2 * p);
            unsigned v3 = *(const unsigned*)(xw1 + (size_t)s3 * 64 + 2 * p);
            ax += (bflo(v0) + bflo(v1)) + (bflo(v2) + bflo(v3));
            ay += (bfhi(v0) + bfhi(v1)) + (bfhi(v2) + bfhi(v3));
        }
        for (; i + 2 <= end; i += 2) {
            int s0 = __builtin_nontemporal_load(csr16 + i + gsl);
            unsigned v0 = *(const unsigned*)(xw1 + (size_t)s0 * 64 + 2 * p);
            ax += bflo(v0);
            ay += bfhi(v0);
        }
        if (i < end && gsl == 0) {
            int s0 = __builtin_nontemporal_load(csr16 + i);
            unsigned v0 = *(const unsigned*)(xw1 + (size_t)s0 * 64 + 2 * p);
            ax += bflo(v0);
            ay += bfhi(v0);
        }
        ax += __shfl_xor(ax, 32);
        ay += __shfl_xor(ay, 32);
        if (gsl == 0) {
            float nin = norm_in[n];
            gs[nl][2 * p]     = fmaxf(ax * nin + b1[2 * p], 0.f);
            gs[nl][2 * p + 1] = fmaxf(ay * nin + b1[2 * p + 1], 0.f);
        }
    }
    __syncthreads();

    const int o = tid & 31;
    const int r = tid >> 5;     // 0..7 -> rows r and r+8
    float a0 = 0.f, a1 = 0.f;
#pragma unroll 8
    for (int k = 0; k < 64; ++k) {
        float wv = ws[k * 32 + o];
        a0 += gs[r][k] * wv;
        a1 += gs[r + 8][k] * wv;
    }
    int row0 = n0 + r, row1 = n0 + r + 8;
    xw2[(size_t)row0 * 32 + o] = f2bf(a0 * norm_out[row0]);
    xw2[(size_t)row1 * 32 + o] = f2bf(a1 * norm_out[row1]);
}

// ---------------- gather32 + weighted partial: 16 nodes/block, 16-edge-deep MLP ----------------
__global__ __launch_bounds__(256) void gather32_kernel(const int* __restrict__ row_start,
                                                       const u16* __restrict__ csr16,
                                                       const u16* __restrict__ xw2,
                                                       const float* __restrict__ norm_in,
                                                       const float* __restrict__ b2,
                                                       const float* __restrict__ fc_w,
                                                       float* __restrict__ red) {
    __shared__ float sout[OUTF];
    const int tid = threadIdx.x;
    if (tid < OUTF) sout[tid] = 0.f;
    __syncthreads();

    const int w = tid >> 6;
    const int l = tid & 63;
    const int p = l & 15;       // feature pair -> feats 2p, 2p+1
    const int gsl = l >> 4;     // edge slot 0..3
    const int n0 = blockIdx.x * 16;
    float tx = 0.f, ty = 0.f;

#pragma unroll
    for (int i4 = 0; i4 < 4; ++i4) {
        int n = n0 + w * 4 + i4;
        int beg = row_start[n], end = row_start[n + 1];
        float ax = 0.f, ay = 0.f;
        int i = beg;
        for (; i + 16 <= end; i += 16) {        // 4 loads in flight
            int s0 = __builtin_nontemporal_load(csr16 + i + gsl);
            int s1 = __builtin_nontemporal_load(csr16 + i + 4 + gsl);
            int s2 = __builtin_nontemporal_load(csr16 + i + 8 + gsl);
            int s3 = __builtin_nontemporal_load(csr16 + i + 12 + gsl);
            unsigned v0 = *(const unsigned*)(xw2 + (size_t)s0 * 32 + 2 * p);
            unsigned v1 = *(const unsigned*)(xw2 + (size_t)s1 * 32 + 2 * p);
            unsigned v2 = *(const unsigned*)(xw2 + (size_t)s2 * 32 + 2 * p);
            unsigned v3 = *(const unsigned*)(xw2 + (size_t)s3 * 32 + 2 * p);
            ax += (bflo(v0) + bflo(v1)) + (bflo(v2) + bflo(v3));
            ay += (bfhi(v0) + bfhi(v1)) + (bfhi(v2) + bfhi(v3));
        }
        for (; i + 8 <= end; i += 8) {
            int s0 = __builtin_nontemporal_load(csr16 + i + gsl);
            int s1 = __builtin_nontemporal_load(csr16 + i + 4 + gsl);
            unsigned v0 = *(const unsigned*)(xw2 + (size_t)s0 * 32 + 2 * p);
            unsigned v1 = *(const unsigned*)(xw2 + (size_t)s1 * 32 + 2 * p);
            ax += bflo(v0) + bflo(v1);
            ay += bfhi(v0) + bfhi(v1);
        }
        for (; i + 4 <= end; i += 4) {
            int s0 = __builtin_nontemporal_load(csr16 + i + gsl);
            unsigned v0 = *(const unsigned*)(xw2 + (size_t)s0 * 32 + 2 * p);
            ax += bflo(v0);
            ay += bfhi(v0);
        }
        int t = end - i;
        if (gsl < t) {
            int s0 = __builtin_nontemporal_load(csr16 + i + gsl);
            unsigned v0 = *(const unsigned*)(xw2 + (size_t)s0 * 32 + 2 * p);
            ax += bflo(v0);
            ay += bfhi(v0);
        }
        ax += __shfl_xor(ax, 16); ax += __shfl_xor(ax, 32);
        ay += __shfl_xor(ay, 16); ay += __shfl_xor(ay, 32);
        if (gsl == 0) {
            float nin = norm_in[n], fw = fc_w[n];
            tx += fmaxf(ax * nin + b2[2 * p], 0.f) * fw;
            ty += fmaxf(ay * nin + b2[2 * p + 1], 0.f) * fw;
        }
    }
    if (gsl == 0) {
        atomicAdd(&sout[2 * p], tx);        // LDS atomics, 4 waves -> 4-way
        atomicAdd(&sout[2 * p + 1], ty);
    }
    __syncthreads();
    if (tid < OUTF) red[(size_t)blockIdx.x * OUTF + tid] = sout[tid];
}

// ---------------- final: 32 blocks, block o sums column o of red ----------------
__global__ __launch_bounds__(256) void reduce2_kernel(const float* __restrict__ red,
                                                      const float* __restrict__ fc_b,
                                                      float* __restrict__ out) {
    __shared__ float s[256];
    const int tid = threadIdx.x;
    const int o = blockIdx.x;       // feature 0..31
    float a = 0.f;
    for (int r = tid; r < G32_BLOCKS; r += 256)
        a += red[(size_t)r * OUTF + o];
    s[tid] = a;
    __syncthreads();
#pragma unroll
    for (int off = 128; off > 0; off >>= 1) {
        if (tid < off) s[tid] += s[tid + off];
        __syncthreads();
    }
    if (tid == 0) out[o] = s[0] + fc_b[0];
}

extern "C" void kernel_launch(void* const* d_in, const int* in_sizes, int n_in,
                              void* d_out, int out_size, void* d_ws, size_t ws_size,
                              hipStream_t stream) {
    const float* x    = (const float*)d_in[0];
    const int*   src  = (const int*)d_in[1];
    const int*   dst  = (const int*)d_in[2];
    const float* W1   = (const float*)d_in[3];
    const float* b1   = (const float*)d_in[4];
    const float* W2   = (const float*)d_in[5];
    const float* b2   = (const float*)d_in[6];
    const float* fc_w = (const float*)d_in[7];
    const float* fc_b = (const float*)d_in[8];
    float* out = (float*)d_out;

    // ---- workspace layout (all 4B-aligned) ----
    u16* csr16      = (u16*)d_ws;                       // 800000 u16 (1.6 MB)
    int* row_start  = (int*)(csr16 + 800000);           // 50001 (+pad)
    int* block_sums = row_start + 50004;                // 256 (+pad)
    u16* xw1_buf    = (u16*)(block_sums + 260);         // 3.2M u16 (6.4 MB)
    u16* xw2_buf    = xw1_buf + 3200000;                // 1.6M u16 (3.2 MB)
    float* norm_out = (float*)(xw2_buf + 1600000);      // 50000
    float* norm_in  = norm_out + 50000;                 // 50000
    float* red      = norm_in + 50000;                  // 3125*32 = 100000
    unsigned char* partial = (unsigned char*)(red + 100000); // 2*64*51200 B
    unsigned char* rel = partial + (size_t)NSLICE * PSTRIDE;

    // ---- CSR build (no global atomics anywhere) ----
    hist_kernel<<<NSLICE * HRANGE * 2, 512, 0, stream>>>(src, dst, partial);
    reduce_scan_kernel<<<SCAN_BLOCKS, 256, 0, stream>>>(partial, row_start, block_sums,
                                                        norm_out, norm_in);
    scan3_kernel<<<SCAN_BLOCKS, 256, 0, stream>>>(row_start, block_sums);
    fill_csr_kernel<<<NSLICE * NRANGE, 512, 0, stream>>>(src, dst, row_start, rel, csr16);

    // ---- layer 1 GEMM (bf16 MFMA) ----
    gemm1_kernel<<<(N_NODES + 63) / 64, 256, 0, stream>>>(x, W1, norm_out, xw1_buf);

    // ---- fused gather64 + gemm2 ----
    gather64_gemm2_kernel<<<N_NODES / 16, 256, 0, stream>>>(row_start, csr16, xw1_buf,
                                                            norm_in, b1, W2, norm_out,
                                                            xw2_buf);

    // ---- gather32 partials + final reduce ----
    gather32_kernel<<<G32_BLOCKS, 256, 0, stream>>>(row_start, csr16, xw2_buf,
                                                    norm_in, b2, fc_w, red);
    reduce2_kernel<<<OUTF, 256, 0, stream>>>(red, fc_b, out);
}

// Round 20
// 130.285 us; speedup vs baseline: 1.2591x; 1.1264x over previous
//
#include <hip/hip_runtime.h>

#define N_NODES 50000
#define N_EDGES 800000
#define IN_FEATS 256
#define HIDDEN 64
#define OUTF 32
#define SCAN_BLOCKS 196     // ceil(50000/256)

#define NSLICE 64           // edge slices
#define SLICE_E 12500       // N_EDGES / NSLICE
#define NRANGE 4            // node ranges for fill_csr
#define RANGE_N 12800       // nodes per fill range
#define PSTRIDE 51200       // per-slice stride in partial arrays

#define HRANGE 2            // hist ranges (packed 2 nodes/int)
#define HRANGE_N 25600      // nodes per hist range

#define G32_BLOCKS 3125     // N_NODES / 16
#define ECAP 1088           // LDS edge-stage capacity per block (mean 256)

typedef __attribute__((ext_vector_type(8))) short bf16x8;
typedef __attribute__((ext_vector_type(4))) float f32x4;
typedef unsigned short u16;

__device__ __forceinline__ unsigned f2bf_pk(float a, float b) {
    union { float f; unsigned u; } x, y;
    x.f = a; y.f = b;
    unsigned lo = x.u + 0x7FFFu + ((x.u >> 16) & 1u);
    unsigned hi = y.u + 0x7FFFu + ((y.u >> 16) & 1u);
    return (lo >> 16) | (hi & 0xFFFF0000u);
}
__device__ __forceinline__ u16 f2bf(float a) {
    union { float f; unsigned u; } x;
    x.f = a;
    return (u16)((x.u + 0x7FFFu + ((x.u >> 16) & 1u)) >> 16);
}
__device__ __forceinline__ float bflo(unsigned v) {
    union { unsigned u; float f; } x; x.u = v << 16; return x.f;
}
__device__ __forceinline__ float bfhi(unsigned v) {
    union { unsigned u; float f; } x; x.u = v & 0xFFFF0000u; return x.f;
}

// ---------------- LDS histogram, 2 nodes packed per int ----------------
__global__ __launch_bounds__(512) void hist_kernel(const int* __restrict__ src,
                                                   const int* __restrict__ dst,
                                                   unsigned char* __restrict__ partial) {
    __shared__ int h[HRANGE_N / 2];     // 12800 ints = 51.2 KB
    const int bid = blockIdx.x;
    const int which = bid & 1;
    const int r = (bid >> 1) & 1;
    const int s = bid >> 2;
    const int tid = threadIdx.x;
    const int lo = r * HRANGE_N;

    for (int i = tid; i < HRANGE_N / 2; i += 512) h[i] = 0;
    __syncthreads();

    const int* arr = which ? dst : src;
    const int e0 = s * SLICE_E;
    for (int j = tid; j < SLICE_E; j += 512) {
        int v = arr[e0 + j] - lo;
        if ((unsigned)v < HRANGE_N) atomicAdd(&h[v >> 1], 1 << ((v & 1) << 4));
    }
    __syncthreads();

    unsigned char* p = partial + (size_t)which * NSLICE * PSTRIDE + (size_t)s * PSTRIDE + lo;
    for (int i = tid; i < HRANGE_N / 2; i += 512) {
        int c = h[i];
        p[i * 2 + 0] = (unsigned char)(c & 0xFFFF);
        p[i * 2 + 1] = (unsigned char)((unsigned)c >> 16);
    }
}

// ---------------- reduce partials -> norms + block-level exclusive scan ----------------
__global__ __launch_bounds__(256) void reduce_scan_kernel(unsigned char* __restrict__ partial,
                                                          int* __restrict__ row_start,
                                                          int* __restrict__ block_sums,
                                                          float* __restrict__ norm_out,
                                                          float* __restrict__ norm_in) {
    __shared__ int sh[256];
    int i = blockIdx.x * 256 + threadIdx.x;
    int run = 0;
    if (i < N_NODES) {
        const unsigned char* ps = partial + i;                      // src partials
        unsigned char* pd = partial + (size_t)NSLICE * PSTRIDE + i; // dst partials
        int so = 0;
#pragma unroll 8
        for (int s = 0; s < NSLICE; ++s) so += ps[(size_t)s * PSTRIDE];
        norm_out[i] = rsqrtf(fmaxf((float)so, 1.0f));
#pragma unroll 8
        for (int s = 0; s < NSLICE; ++s) {
            int c = pd[(size_t)s * PSTRIDE];
            pd[(size_t)s * PSTRIDE] = (unsigned char)run;   // exclusive prefix
            run += c;
        }
        norm_in[i] = rsqrtf(fmaxf((float)run, 1.0f));
    }
    sh[threadIdx.x] = run;
    __syncthreads();
#pragma unroll
    for (int off = 1; off < 256; off <<= 1) {
        int t = (threadIdx.x >= off) ? sh[threadIdx.x - off] : 0;
        __syncthreads();
        sh[threadIdx.x] += t;
        __syncthreads();
    }
    if (i < N_NODES) row_start[i] = sh[threadIdx.x] - run;
    if (threadIdx.x == 255) block_sums[blockIdx.x] = sh[255];
}

// ---------------- scan of block sums folded into the add pass ----------------
__global__ __launch_bounds__(256) void scan3_kernel(int* __restrict__ row_start,
                                                    const int* __restrict__ block_sums) {
    __shared__ int s[256];
    int v = (threadIdx.x < SCAN_BLOCKS) ? block_sums[threadIdx.x] : 0;
    s[threadIdx.x] = v;
    __syncthreads();
#pragma unroll
    for (int off = 1; off < 256; off <<= 1) {
        int t = (threadIdx.x >= off) ? s[threadIdx.x - off] : 0;
        __syncthreads();
        s[threadIdx.x] += t;
        __syncthreads();
    }
    int base = (blockIdx.x == 0) ? 0 : s[blockIdx.x - 1];   // exclusive prefix for this block
    int i = blockIdx.x * 256 + threadIdx.x;
    if (i < N_NODES) row_start[i] += base;
    if (i == 0) row_start[N_NODES] = N_EDGES;
}

// ---------------- CSR fill with LDS cursors (u16 ids): block = (slice, range) ----------------
__global__ __launch_bounds__(512) void fill_csr_kernel(const int* __restrict__ src,
                                                       const int* __restrict__ dst,
                                                       const int* __restrict__ row_start,
                                                       const unsigned char* __restrict__ rel,
                                                       u16* __restrict__ csr16) {
    __shared__ int cur[RANGE_N];        // 51200 B
    const int bid = blockIdx.x;
    const int r = bid & 3;
    const int s = bid >> 2;
    const int tid = threadIdx.x;
    const int lo = r * RANGE_N;

    const unsigned char* relp = rel + (size_t)s * PSTRIDE;
    for (int i = tid; i < RANGE_N; i += 512) {
        int node = lo + i;
        cur[i] = (node < N_NODES) ? row_start[node] + (int)relp[node] : 0;
    }
    __syncthreads();

    const int e0 = s * SLICE_E;
    for (int j = tid; j < SLICE_E; j += 512) {
        int d = dst[e0 + j] - lo;
        if ((unsigned)d < RANGE_N) {
            int pos = atomicAdd(&cur[d], 1);
            csr16[pos] = (u16)src[e0 + j];
        }
    }
}

// ---------------- GEMM1: bf16 MFMA 16x16x32, 64x64 tile, 2 chunks of BK=128 ----------------
#define AST 136    // shorts per LDS row
__global__ __launch_bounds__(256) void gemm1_kernel(const float* __restrict__ x,
                                                    const float* __restrict__ W1,
                                                    const float* __restrict__ norm_out,
                                                    u16* __restrict__ xw1) {
    __shared__ short As[64 * AST];   // x tile, bf16, [row][k]
    __shared__ short Bt[64 * AST];   // W1 chunk, bf16, [col][k]
    const int tid = threadIdx.x;
    const int n0 = blockIdx.x * 64;

    const f32x4 zero4 = {0.f, 0.f, 0.f, 0.f};
    f32x4 acc[4] = {zero4, zero4, zero4, zero4};

    const int srow = tid >> 2;          // staging row 0..63
    const int sseg = tid & 3;           // 32-k segment
    const int grow = n0 + srow;
    const bool grow_ok = grow < N_NODES;

    const int w = tid >> 6;             // wave 0..3 -> rows w*16..
    const int l = tid & 63;

    for (int c = 0; c < 2; ++c) {
        if (c) __syncthreads();
        {
            const float* xp = x + (size_t)grow * IN_FEATS + c * 128 + sseg * 32;
            short* ap = As + srow * AST + sseg * 32;
#pragma unroll
            for (int j = 0; j < 8; ++j) {
                float4 v = make_float4(0.f, 0.f, 0.f, 0.f);
                if (grow_ok) v = *(const float4*)(xp + j * 4);
                unsigned p0 = f2bf_pk(v.x, v.y);
                unsigned p1 = f2bf_pk(v.z, v.w);
                *(uint2*)(ap + j * 4) = make_uint2(p0, p1);
            }
        }
        {
#pragma unroll
            for (int it = 0; it < 16; ++it) {
                int flat = tid + it * 256;
                int kp = flat >> 6;             // k-pair 0..63
                int col = flat & 63;
                int k = c * 128 + kp * 2;
                float w0 = W1[(size_t)k * HIDDEN + col];
                float w1 = W1[(size_t)(k + 1) * HIDDEN + col];
                *(unsigned*)(Bt + col * AST + kp * 2) = f2bf_pk(w0, w1);
            }
        }
        __syncthreads();

        const short* ap = As + (w * 16 + (l & 15)) * AST + (l >> 4) * 8;
        const short* bp = Bt + (l & 15) * AST + (l >> 4) * 8;
#pragma unroll
        for (int ks = 0; ks < 4; ++ks) {
            bf16x8 af = *(const bf16x8*)(ap + ks * 32);
#pragma unroll
            for (int ct = 0; ct < 4; ++ct) {
                bf16x8 bfv = *(const bf16x8*)(bp + ct * 16 * AST + ks * 32);
                acc[ct] = __builtin_amdgcn_mfma_f32_16x16x32_bf16(af, bfv, acc[ct], 0, 0, 0);
            }
        }
    }

    const int rbase = n0 + w * 16 + (l >> 4) * 4;
    const int cbase = l & 15;
#pragma unroll
    for (int j = 0; j < 4; ++j) {
        int row = rbase + j;
        if (row < N_NODES) {
            float nrm = norm_out[row];
            u16* orow = xw1 + (size_t)row * HIDDEN + cbase;
#pragma unroll
            for (int ct = 0; ct < 4; ++ct)
                orow[ct * 16] = f2bf(acc[ct][j] * nrm);
        }
    }
}

// ---------------- fused gather64 + gemm2: 16 nodes/block, LDS edge staging ----------------
__global__ __launch_bounds__(256) void gather64_gemm2_kernel(const int* __restrict__ row_start,
                                                             const u16* __restrict__ csr16,
                                                             const u16* __restrict__ xw1,
                                                             const float* __restrict__ norm_in,
                                                             const float* __restrict__ b1,
                                                             const float* __restrict__ W2,
                                                             const float* __restrict__ norm_out,
                                                             u16* __restrict__ xw2) {
    __shared__ float gs[16][68];         // g1 tile
    __shared__ float ws[HIDDEN * OUTF];  // W2, 8 KB
    __shared__ u16 eidx[ECAP];           // block edge list (contiguous csr range)
    const int tid = threadIdx.x;
#pragma unroll
    for (int i = 0; i < 8; ++i) ws[tid + i * 256] = W2[tid + i * 256];

    const int n0 = blockIdx.x * 16;
    const int ebeg = row_start[n0];
    const int ne = row_start[n0 + 16] - ebeg;
    const bool lds_ok = ne <= ECAP;
    if (lds_ok)
        for (int i = tid; i < ne; i += 256) eidx[i] = csr16[ebeg + i];
    __syncthreads();

#define EIDX64(j) (lds_ok ? (int)eidx[(j) - ebeg] : (int)csr16[j])

    const int w = tid >> 6;
    const int l = tid & 63;
    const int p = l & 31;       // feature pair -> feats 2p, 2p+1
    const int gsl = l >> 5;     // edge slot 0/1

#pragma unroll
    for (int i4 = 0; i4 < 4; ++i4) {
        int nl = w * 4 + i4;
        int n = n0 + nl;
        int beg = row_start[n], end = row_start[n + 1];
        float ax = 0.f, ay = 0.f;
        int i = beg;
        for (; i + 16 <= end; i += 16) {        // 8 loads in flight
            int s0 = EIDX64(i + 0 + gsl),  s1 = EIDX64(i + 2 + gsl);
            int s2 = EIDX64(i + 4 + gsl),  s3 = EIDX64(i + 6 + gsl);
            int s4 = EIDX64(i + 8 + gsl),  s5 = EIDX64(i + 10 + gsl);
            int s6 = EIDX64(i + 12 + gsl), s7 = EIDX64(i + 14 + gsl);
            unsigned v0 = *(const unsigned*)(xw1 + (size_t)s0 * 64 + 2 * p);
            unsigned v1 = *(const unsigned*)(xw1 + (size_t)s1 * 64 + 2 * p);
            unsigned v2 = *(const unsigned*)(xw1 + (size_t)s2 * 64 + 2 * p);
            unsigned v3 = *(const unsigned*)(xw1 + (size_t)s3 * 64 + 2 * p);
            unsigned v4 = *(const unsigned*)(xw1 + (size_t)s4 * 64 + 2 * p);
            unsigned v5 = *(const unsigned*)(xw1 + (size_t)s5 * 64 + 2 * p);
            unsigned v6 = *(const unsigned*)(xw1 + (size_t)s6 * 64 + 2 * p);
            unsigned v7 = *(const unsigned*)(xw1 + (size_t)s7 * 64 + 2 * p);
            ax += ((bflo(v0) + bflo(v1)) + (bflo(v2) + bflo(v3))) +
                  ((bflo(v4) + bflo(v5)) + (bflo(v6) + bflo(v7)));
            ay += ((bfhi(v0) + bfhi(v1)) + (bfhi(v2) + bfhi(v3))) +
                  ((bfhi(v4) + bfhi(v5)) + (bfhi(v6) + bfhi(v7)));
        }
        for (; i + 8 <= end; i += 8) {
            int s0 = EIDX64(i + gsl);
            int s1 = EIDX64(i + 2 + gsl);
            int s2 = EIDX64(i + 4 + gsl);
            int s3 = EIDX64(i + 6 + gsl);
            unsigned v0 = *(const unsigned*)(xw1 + (size_t)s0 * 64 + 2 * p);
            unsigned v1 = *(const unsigned*)(xw1 + (size_t)s1 * 64 + 2 * p);
            unsigned v2 = *(const unsigned*)(xw1 + (size_t)s2 * 64 + 2 * p);
            unsigned v3 = *(const unsigned*)(xw1 + (size_t)s3 * 64 + 2 * p);
            ax += (bflo(v0) + bflo(v1)) + (bflo(v2) + bflo(v3));
            ay += (bfhi(v0) + bfhi(v1)) + (bfhi(v2) + bfhi(v3));
        }
        for (; i + 2 <= end; i += 2) {
            int s0 = EIDX64(i + gsl);
            unsigned v0 = *(const unsigned*)(xw1 + (size_t)s0 * 64 + 2 * p);
            ax += bflo(v0);
            ay += bfhi(v0);
        }
        if (i < end && gsl == 0) {
            int s0 = EIDX64(i);
            unsigned v0 = *(const unsigned*)(xw1 + (size_t)s0 * 64 + 2 * p);
            ax += bflo(v0);
            ay += bfhi(v0);
        }
        ax += __shfl_xor(ax, 32);
        ay += __shfl_xor(ay, 32);
        if (gsl == 0) {
            float nin = norm_in[n];
            gs[nl][2 * p]     = fmaxf(ax * nin + b1[2 * p], 0.f);
            gs[nl][2 * p + 1] = fmaxf(ay * nin + b1[2 * p + 1], 0.f);
        }
    }
#undef EIDX64
    __syncthreads();

    const int o = tid & 31;
    const int r = tid >> 5;     // 0..7 -> rows r and r+8
    float a0 = 0.f, a1 = 0.f;
#pragma unroll 8
    for (int k = 0; k < 64; ++k) {
        float wv = ws[k * 32 + o];
        a0 += gs[r][k] * wv;
        a1 += gs[r + 8][k] * wv;
    }
    int row0 = n0 + r, row1 = n0 + r + 8;
    xw2[(size_t)row0 * 32 + o] = f2bf(a0 * norm_out[row0]);
    xw2[(size_t)row1 * 32 + o] = f2bf(a1 * norm_out[row1]);
}

// ---------------- gather32 + weighted partial: 16 nodes/block, LDS edge staging ----------------
__global__ __launch_bounds__(256) void gather32_kernel(const int* __restrict__ row_start,
                                                       const u16* __restrict__ csr16,
                                                       const u16* __restrict__ xw2,
                                                       const float* __restrict__ norm_in,
                                                       const float* __restrict__ b2,
                                                       const float* __restrict__ fc_w,
                                                       float* __restrict__ red) {
    __shared__ float sout[OUTF];
    __shared__ u16 eidx[ECAP];
    const int tid = threadIdx.x;
    if (tid < OUTF) sout[tid] = 0.f;

    const int n0 = blockIdx.x * 16;
    const int ebeg = row_start[n0];
    const int ne = row_start[n0 + 16] - ebeg;
    const bool lds_ok = ne <= ECAP;
    if (lds_ok)
        for (int i = tid; i < ne; i += 256) eidx[i] = csr16[ebeg + i];
    __syncthreads();

#define EIDX32(j) (lds_ok ? (int)eidx[(j) - ebeg] : (int)csr16[j])

    const int w = tid >> 6;
    const int l = tid & 63;
    const int p = l & 15;       // feature pair -> feats 2p, 2p+1
    const int gsl = l >> 4;     // edge slot 0..3
    float tx = 0.f, ty = 0.f;

#pragma unroll
    for (int i4 = 0; i4 < 4; ++i4) {
        int n = n0 + w * 4 + i4;
        int beg = row_start[n], end = row_start[n + 1];
        float ax = 0.f, ay = 0.f;
        int i = beg;
        for (; i + 16 <= end; i += 16) {        // 4 loads in flight
            int s0 = EIDX32(i + gsl);
            int s1 = EIDX32(i + 4 + gsl);
            int s2 = EIDX32(i + 8 + gsl);
            int s3 = EIDX32(i + 12 + gsl);
            unsigned v0 = *(const unsigned*)(xw2 + (size_t)s0 * 32 + 2 * p);
            unsigned v1 = *(const unsigned*)(xw2 + (size_t)s1 * 32 + 2 * p);
            unsigned v2 = *(const unsigned*)(xw2 + (size_t)s2 * 32 + 2 * p);
            unsigned v3 = *(const unsigned*)(xw2 + (size_t)s3 * 32 + 2 * p);
            ax += (bflo(v0) + bflo(v1)) + (bflo(v2) + bflo(v3));
            ay += (bfhi(v0) + bfhi(v1)) + (bfhi(v2) + bfhi(v3));
        }
        for (; i + 8 <= end; i += 8) {
            int s0 = EIDX32(i + gsl);
            int s1 = EIDX32(i + 4 + gsl);
            unsigned v0 = *(const unsigned*)(xw2 + (size_t)s0 * 32 + 2 * p);
            unsigned v1 = *(const unsigned*)(xw2 + (size_t)s1 * 32 + 2 * p);
            ax += bflo(v0) + bflo(v1);
            ay += bfhi(v0) + bfhi(v1);
        }
        for (; i + 4 <= end; i += 4) {
            int s0 = EIDX32(i + gsl);
            unsigned v0 = *(const unsigned*)(xw2 + (size_t)s0 * 32 + 2 * p);
            ax += bflo(v0);
            ay += bfhi(v0);
        }
        int t = end - i;
        if (gsl < t) {
            int s0 = EIDX32(i + gsl);
            unsigned v0 = *(const unsigned*)(xw2 + (size_t)s0 * 32 + 2 * p);
            ax += bflo(v0);
            ay += bfhi(v0);
        }
        ax += __shfl_xor(ax, 16); ax += __shfl_xor(ax, 32);
        ay += __shfl_xor(ay, 16); ay += __shfl_xor(ay, 32);
        if (gsl == 0) {
            float nin = norm_in[n], fw = fc_w[n];
            tx += fmaxf(ax * nin + b2[2 * p], 0.f) * fw;
            ty += fmaxf(ay * nin + b2[2 * p + 1], 0.f) * fw;
        }
    }
#undef EIDX32
    if (gsl == 0) {
        atomicAdd(&sout[2 * p], tx);        // LDS atomics, 4 waves -> 4-way
        atomicAdd(&sout[2 * p + 1], ty);
    }
    __syncthreads();
    if (tid < OUTF) red[(size_t)blockIdx.x * OUTF + tid] = sout[tid];
}

// ---------------- final: 32 blocks, block o sums column o of red ----------------
__global__ __launch_bounds__(256) void reduce2_kernel(const float* __restrict__ red,
                                                      const float* __restrict__ fc_b,
                                                      float* __restrict__ out) {
    __shared__ float s[256];
    const int tid = threadIdx.x;
    const int o = blockIdx.x;       // feature 0..31
    float a = 0.f;
    for (int r = tid; r < G32_BLOCKS; r += 256)
        a += red[(size_t)r * OUTF + o];
    s[tid] = a;
    __syncthreads();
#pragma unroll
    for (int off = 128; off > 0; off >>= 1) {
        if (tid < off) s[tid] += s[tid + off];
        __syncthreads();
    }
    if (tid == 0) out[o] = s[0] + fc_b[0];
}

extern "C" void kernel_launch(void* const* d_in, const int* in_sizes, int n_in,
                              void* d_out, int out_size, void* d_ws, size_t ws_size,
                              hipStream_t stream) {
    const float* x    = (const float*)d_in[0];
    const int*   src  = (const int*)d_in[1];
    const int*   dst  = (const int*)d_in[2];
    const float* W1   = (const float*)d_in[3];
    const float* b1   = (const float*)d_in[4];
    const float* W2   = (const float*)d_in[5];
    const float* b2   = (const float*)d_in[6];
    const float* fc_w = (const float*)d_in[7];
    const float* fc_b = (const float*)d_in[8];
    float* out = (float*)d_out;

    // ---- workspace layout (all 4B-aligned) ----
    u16* csr16      = (u16*)d_ws;                       // 800000 u16 (1.6 MB)
    int* row_start  = (int*)(csr16 + 800000);           // 50001 (+pad)
    int* block_sums = row_start + 50004;                // 256 (+pad)
    u16* xw1_buf    = (u16*)(block_sums + 260);         // 3.2M u16 (6.4 MB)
    u16* xw2_buf    = xw1_buf + 3200000;                // 1.6M u16 (3.2 MB)
    float* norm_out = (float*)(xw2_buf + 1600000);      // 50000
    float* norm_in  = norm_out + 50000;                 // 50000
    float* red      = norm_in + 50000;                  // 3125*32 = 100000
    unsigned char* partial = (unsigned char*)(red + 100000); // 2*64*51200 B
    unsigned char* rel = partial + (size_t)NSLICE * PSTRIDE;

    // ---- CSR build (no global atomics anywhere) ----
    hist_kernel<<<NSLICE * HRANGE * 2, 512, 0, stream>>>(src, dst, partial);
    reduce_scan_kernel<<<SCAN_BLOCKS, 256, 0, stream>>>(partial, row_start, block_sums,
                                                        norm_out, norm_in);
    scan3_kernel<<<SCAN_BLOCKS, 256, 0, stream>>>(row_start, block_sums);
    fill_csr_kernel<<<NSLICE * NRANGE, 512, 0, stream>>>(src, dst, row_start, rel, csr16);

    // ---- layer 1 GEMM (bf16 MFMA) ----
    gemm1_kernel<<<(N_NODES + 63) / 64, 256, 0, stream>>>(x, W1, norm_out, xw1_buf);

    // ---- fused gather64 + gemm2 ----
    gather64_gemm2_kernel<<<N_NODES / 16, 256, 0, stream>>>(row_start, csr16, xw1_buf,
                                                            norm_in, b1, W2, norm_out,
                                                            xw2_buf);

    // ---- gather32 partials + final reduce ----
    gather32_kernel<<<G32_BLOCKS, 256, 0, stream>>>(row_start, csr16, xw2_buf,
                                                    norm_in, b2, fc_w, red);
    reduce2_kernel<<<OUTF, 256, 0, stream>>>(red, fc_b, out);
}